// Round 1
// baseline (9390.173 us; speedup 1.0000x reference)
//
#include <hip/hip_runtime.h>

#define NV 100000
#define ND 300
#define NH 512
#define NB 25
#define NT 600
#define NM 15000   // NB*NT
#define NG 1536    // 3*NH

typedef _Float16 v8h __attribute__((ext_vector_type(8)));
typedef _Float16 v4h __attribute__((ext_vector_type(4)));
typedef float    v4f __attribute__((ext_vector_type(4)));

static __device__ __forceinline__ v8h mk8(v4h a, v4h b) {
  v8h r;
  r[0]=a[0]; r[1]=a[1]; r[2]=a[2]; r[3]=a[3];
  r[4]=b[0]; r[5]=b[1]; r[6]=b[2]; r[7]=b[3];
  return r;
}

// ---------------- barrier init ----------------
__global__ void k_init(unsigned* bar) {
  if (threadIdx.x < 32) bar[threadIdx.x] = 0u;
}

// ---------------- GEMM: Cxg[m][n] = sum_k A[m][k]*Bw[n][k] + bias[n], f16 out ----
// MODE 0: A = emb[words[m]] (f32, K=300). MODE 1: A = Af16 [NM][512] (f16).
template<int MODE>
__global__ __launch_bounds__(256) void k_gemm(
    const int* __restrict__ words, const float* __restrict__ emb,
    const _Float16* __restrict__ Af16,
    const float* __restrict__ Bw, const float* __restrict__ bias,
    _Float16* __restrict__ Cxg)
{
  constexpr int K   = (MODE == 0) ? ND : 512;
  constexpr int NKT = (K + 31) / 32;
  __shared__ _Float16 As[128][40];   // stride 40 f16 = 80B: 16B-aligned rows, <=2-way banks
  __shared__ _Float16 Bh[128][40];
  __shared__ _Float16 Bl[128][40];
  const int tid = threadIdx.x;
  const int m0 = blockIdx.x * 128, n0 = blockIdx.y * 128;
  const int w = tid >> 6, l = tid & 63;
  const int wm = w >> 1, wn = w & 1;
  const int l15 = l & 15, q = l >> 4;

  v4f accH[4][4], accL[4][4];
  for (int a = 0; a < 4; ++a)
    for (int b = 0; b < 4; ++b) {
      v4f z = {0.f, 0.f, 0.f, 0.f};
      accH[a][b] = z; accL[a][b] = z;
    }

#pragma unroll 1
  for (int kt = 0; kt < NKT; ++kt) {
    const int kb = kt * 32;
    // ---- stage A + B tiles (f32 -> f16 split for B) ----
    for (int jj = 0; jj < 4; ++jj) {
      const int F = tid + 256 * jj;      // 0..1023
      const int row = F >> 3;
      const int kl = (F & 7) * 4;
      // A
      if (MODE == 0) {
        const int m = m0 + row;
        float x0 = 0.f, x1 = 0.f, x2 = 0.f, x3 = 0.f;
        if (m < NM) {
          const int word = words[m];
          const float* ap = emb + (long)word * ND + kb + kl;
          if (kb + kl + 3 < K) {
            float4 v = *(const float4*)ap;
            x0 = v.x; x1 = v.y; x2 = v.z; x3 = v.w;
          } else {
            if (kb + kl + 0 < K) x0 = ap[0];
            if (kb + kl + 1 < K) x1 = ap[1];
            if (kb + kl + 2 < K) x2 = ap[2];
            if (kb + kl + 3 < K) x3 = ap[3];
          }
        }
        v4h hv; hv[0]=(_Float16)x0; hv[1]=(_Float16)x1; hv[2]=(_Float16)x2; hv[3]=(_Float16)x3;
        *(v4h*)&As[row][kl] = hv;
      } else {
        const int m = m0 + row;
        v4h hv; hv[0]=(_Float16)0; hv[1]=(_Float16)0; hv[2]=(_Float16)0; hv[3]=(_Float16)0;
        if (m < NM) hv = *(const v4h*)(Af16 + (long)m * 512 + kb + kl);
        *(v4h*)&As[row][kl] = hv;
      }
      // B (w_ih rows), split hi/lo
      {
        const int n = n0 + row;
        const float* bp = Bw + (long)n * K + kb + kl;
        float x[4] = {0.f, 0.f, 0.f, 0.f};
        if (kb + kl + 3 < K) {
          float4 v = *(const float4*)bp;
          x[0] = v.x; x[1] = v.y; x[2] = v.z; x[3] = v.w;
        } else {
          for (int c = 0; c < 4; ++c) if (kb + kl + c < K) x[c] = bp[c];
        }
        v4h bh, bl;
        for (int c = 0; c < 4; ++c) {
          _Float16 hi = (_Float16)x[c];
          bh[c] = hi;
          bl[c] = (_Float16)((x[c] - (float)hi) * 1024.f);
        }
        *(v4h*)&Bh[row][kl] = bh;
        *(v4h*)&Bl[row][kl] = bl;
      }
    }
    __syncthreads();
    // ---- MFMA ----
    v8h af[4];
    for (int mt = 0; mt < 4; ++mt) {
      const int r = wm * 64 + mt * 16 + l15;
      af[mt] = *(const v8h*)&As[r][q * 8];     // 16B-aligned (row stride 80B)
    }
    for (int nt = 0; nt < 4; ++nt) {
      const int r = wn * 64 + nt * 16 + l15;
      v8h bh = *(const v8h*)&Bh[r][q * 8];
      v8h bl = *(const v8h*)&Bl[r][q * 8];
      for (int mt = 0; mt < 4; ++mt) {
        accH[mt][nt] = __builtin_amdgcn_mfma_f32_16x16x32_f16(af[mt], bh, accH[mt][nt], 0, 0, 0);
        accL[mt][nt] = __builtin_amdgcn_mfma_f32_16x16x32_f16(af[mt], bl, accL[mt][nt], 0, 0, 0);
      }
    }
    __syncthreads();
  }
  // ---- epilogue ----
  for (int nt = 0; nt < 4; ++nt) {
    const int n = n0 + wn * 64 + nt * 16 + l15;
    const float bv = bias[n];
    for (int mt = 0; mt < 4; ++mt) {
      for (int r = 0; r < 4; ++r) {
        const int m = m0 + wm * 64 + mt * 16 + q * 4 + r;
        if (m < NM) {
          const float cv = accH[mt][nt][r] + accL[mt][nt][r] * (1.f / 1024.f) + bv;
          Cxg[(long)m * NG + n] = (_Float16)cv;
        }
      }
    }
  }
}

// ---------------- persistent GRU scan (one layer) ----------------
// grid 32 blocks x 384 thr. Block owns 16 hidden units (48 W-rows = 3 M-tiles).
// 6 waves = (mt in 0..2) x (nt in 0..1); nt=1 covers batch cols 9..24.
__global__ __launch_bounds__(384) void k_scan(
    const _Float16* __restrict__ xg,   // [NM][NG] f16, includes b_ih
    const float* __restrict__ whh,     // [NG][NH] f32
    const float* __restrict__ bhh,     // [NG]
    const float* __restrict__ hinit,   // [NB][NH] f32 (layer slice of `hidden`)
    unsigned* __restrict__ hpk,        // [2][NB][256] packed f16-pair dwords
    unsigned* __restrict__ outpk,      // [NM][256] packed (layer 0 only)
    float* __restrict__ hfin,          // d_out hidden slice [NB][NH]
    unsigned* __restrict__ bar,        // monotonic barrier counter
    const int write_out)
{
  __shared__ _Float16 hs[NB][516];     // stride 516: 8B-aligned, ~2-4 way banks
  __shared__ float ghs[48][33];
  __shared__ float hprev[NB][16];      // exact fp32 recurrent state (block-local)
  const int tid = threadIdx.x;
  const int u0 = blockIdx.x * 16;
  const int w = tid >> 6, l = tid & 63;
  const int mt = w >> 1, nt = w & 1;
  const int ntb = nt ? 9 : 0;
  const int l15 = l & 15, q = l >> 4;

  // W fragments -> registers, split f16 hi/lo (lo scaled x1024)
  v8h afh[16], afl[16];
  {
    const float* wrow = whh + (long)(mt * 512 + u0 + l15) * 512 + q * 8;
    for (int ks = 0; ks < 16; ++ks) {
      float4 v0 = *(const float4*)(wrow + ks * 32);
      float4 v1 = *(const float4*)(wrow + ks * 32 + 4);
      float xs[8] = {v0.x, v0.y, v0.z, v0.w, v1.x, v1.y, v1.z, v1.w};
      v8h hh, hl;
      for (int j = 0; j < 8; ++j) {
        _Float16 hi = (_Float16)xs[j];
        hh[j] = hi;
        hl[j] = (_Float16)((xs[j] - (float)hi) * 1024.f);
      }
      afh[ks] = hh; afl[ks] = hl;
    }
  }
  // initial h stage
  for (int idx = tid; idx < NB * NH; idx += 384) {
    const int b = idx >> 9, k = idx & 511;
    hs[b][k] = (_Float16)hinit[idx];
  }
  for (int t2 = tid; t2 < 400; t2 += 384) {
    const int b = t2 >> 4, i = t2 & 15;
    hprev[b][i] = hinit[b * 512 + u0 + i];
  }
  __syncthreads();

  const bool ga = (tid < 200);         // gate tasks: (b 0..24) x (j 0..7), 2 units each
  const int gb = tid >> 3, gj = tid & 7;

#pragma unroll 1
  for (int t = 0; t < NT; ++t) {
    // prefetch xg for the gate phase (latency hidden behind MFMA)
    float xr0 = 0.f, xr1 = 0.f, xz0 = 0.f, xz1 = 0.f, xn0 = 0.f, xn1 = 0.f;
    if (ga) {
      const _Float16* xp = xg + (long)(gb * NT + t) * NG + u0 + 2 * gj;
      xr0 = (float)xp[0];    xr1 = (float)xp[1];
      xz0 = (float)xp[512];  xz1 = (float)xp[513];
      xn0 = (float)xp[1024]; xn1 = (float)xp[1025];
    }
    // gh = W_chunk * h^T via MFMA (4 independent acc chains)
    const int bcol = ntb + l15;
    v4f aH0 = {0.f,0.f,0.f,0.f}, aH1 = {0.f,0.f,0.f,0.f};
    v4f aL0 = {0.f,0.f,0.f,0.f}, aL1 = {0.f,0.f,0.f,0.f};
    for (int ks = 0; ks < 16; ks += 2) {
      const int k = ks * 32 + q * 8;
      v8h b0 = mk8(*(const v4h*)&hs[bcol][k],      *(const v4h*)&hs[bcol][k + 4]);
      v8h b1 = mk8(*(const v4h*)&hs[bcol][k + 32], *(const v4h*)&hs[bcol][k + 36]);
      aH0 = __builtin_amdgcn_mfma_f32_16x16x32_f16(afh[ks],     b0, aH0, 0, 0, 0);
      aL0 = __builtin_amdgcn_mfma_f32_16x16x32_f16(afl[ks],     b0, aL0, 0, 0, 0);
      aH1 = __builtin_amdgcn_mfma_f32_16x16x32_f16(afh[ks + 1], b1, aH1, 0, 0, 0);
      aL1 = __builtin_amdgcn_mfma_f32_16x16x32_f16(afl[ks + 1], b1, aL1, 0, 0, 0);
    }
    {
      const int row = mt * 16 + q * 4;
      for (int r = 0; r < 4; ++r)
        ghs[row + r][bcol] = (aH0[r] + aH1[r]) + (aL0[r] + aL1[r]) * (1.f / 1024.f);
    }
    __syncthreads();
    // gate math (fp32), write packed-f16 h via device-scope stores
    if (ga) {
      const int i0 = 2 * gj, i1 = i0 + 1;
      const int ug0 = u0 + i0, ug1 = u0 + i1;
      float hr0 = ghs[i0][gb]      + bhh[ug0];
      float hz0 = ghs[16 + i0][gb] + bhh[512 + ug0];
      float hn0 = ghs[32 + i0][gb] + bhh[1024 + ug0];
      float hr1 = ghs[i1][gb]      + bhh[ug1];
      float hz1 = ghs[16 + i1][gb] + bhh[512 + ug1];
      float hn1 = ghs[32 + i1][gb] + bhh[1024 + ug1];
      float r0 = 1.f / (1.f + __expf(-(xr0 + hr0)));
      float z0 = 1.f / (1.f + __expf(-(xz0 + hz0)));
      float n0 = tanhf(xn0 + r0 * hn0);
      float r1 = 1.f / (1.f + __expf(-(xr1 + hr1)));
      float z1 = 1.f / (1.f + __expf(-(xz1 + hz1)));
      float n1 = tanhf(xn1 + r1 * hn1);
      float hp0 = hprev[gb][i0], hp1 = hprev[gb][i1];
      float h0 = (1.f - z0) * n0 + z0 * hp0;
      float h1 = (1.f - z1) * n1 + z1 * hp1;
      hprev[gb][i0] = h0; hprev[gb][i1] = h1;
      _Float16 f0 = (_Float16)h0, f1 = (_Float16)h1;
      unsigned pk = (unsigned)(*(unsigned short*)&f0) | ((unsigned)(*(unsigned short*)&f1) << 16);
      const int di = gb * 256 + (u0 >> 1) + gj;
      __hip_atomic_store(&hpk[(t & 1) * 6400 + di], pk, __ATOMIC_RELAXED, __HIP_MEMORY_SCOPE_AGENT);
      if (write_out) outpk[(long)(gb * NT + t) * 256 + (u0 >> 1) + gj] = pk;
      if (t == NT - 1) { hfin[gb * 512 + ug0] = h0; hfin[gb * 512 + ug1] = h1; }
    }
    __syncthreads();   // drains each wave's vmcnt before s_barrier -> stores done
    // grid barrier: monotonic counter, no reset race
    if (tid == 0) {
      __hip_atomic_fetch_add(bar, 1u, __ATOMIC_ACQ_REL, __HIP_MEMORY_SCOPE_AGENT);
      const unsigned tgt = 32u * (unsigned)(t + 1);
      while (__hip_atomic_load(bar, __ATOMIC_ACQUIRE, __HIP_MEMORY_SCOPE_AGENT) < tgt)
        __builtin_amdgcn_s_sleep(1);
    }
    __syncthreads();
    // restage h(t+1) from the buffer just written (coherent sc1 loads)
    if (t < NT - 1) {
      for (int idx = tid; idx < 6400; idx += 384) {
        const unsigned pk = __hip_atomic_load(&hpk[(t & 1) * 6400 + idx],
                                              __ATOMIC_RELAXED, __HIP_MEMORY_SCOPE_AGENT);
        const int b = idx >> 8, k2 = (idx & 255) * 2;
        *(unsigned*)&hs[b][k2] = pk;
      }
      __syncthreads();
    }
  }
}

// ---------------- final FC + sigmoid ----------------
__global__ __launch_bounds__(256) void k_final(
    const float* __restrict__ h1, const float* __restrict__ fcw,
    const float* __restrict__ fcb, float* __restrict__ sig)
{
  __shared__ float red[25][8];
  const int tid = threadIdx.x;
  const int b = tid >> 3, p = tid & 7;
  if (b < 25) {
    float s = 0.f;
    for (int k = p * 64; k < p * 64 + 64; ++k) s += h1[b * 512 + k] * fcw[k];
    red[b][p] = s;
  }
  __syncthreads();
  if (b < 25 && p == 0) {
    float d = red[b][0] + red[b][1] + red[b][2] + red[b][3]
            + red[b][4] + red[b][5] + red[b][6] + red[b][7];
    sig[b] = 1.f / (1.f + __expf(-(d + fcb[0])));
  }
}

extern "C" void kernel_launch(void* const* d_in, const int* in_sizes, int n_in,
                              void* d_out, int out_size, void* d_ws, size_t ws_size,
                              hipStream_t stream)
{
  (void)in_sizes; (void)n_in; (void)out_size;
  const int*   words  = (const int*)d_in[0];
  const float* hidden = (const float*)d_in[1];
  const float* emb    = (const float*)d_in[2];
  const float* w_ih0  = (const float*)d_in[3];
  const float* w_hh0  = (const float*)d_in[4];
  const float* b_ih0  = (const float*)d_in[5];
  const float* b_hh0  = (const float*)d_in[6];
  const float* w_ih1  = (const float*)d_in[7];
  const float* w_hh1  = (const float*)d_in[8];
  const float* b_ih1  = (const float*)d_in[9];
  const float* b_hh1  = (const float*)d_in[10];
  const float* fcw    = (const float*)d_in[11];
  const float* fcb    = (const float*)d_in[12];
  float* out = (float*)d_out;
  char* ws = (char*)d_ws;

  // ws layout: [0,256) barriers | XG f16 46.08MB | OUT0 f16 15.36MB | HPK 2x51200B
  const size_t NEED = 256 + 46080000 + 15360000 + 102400;
  if (ws_size < NEED) return;  // scratch too small: fail loudly via absmax, not corruption

  unsigned*  bar  = (unsigned*)ws;
  _Float16*  XG   = (_Float16*)(ws + 256);
  _Float16*  OUT0 = (_Float16*)(ws + 256 + 46080000);
  unsigned*  HPK0 = (unsigned*)(ws + 256 + 46080000 + 15360000);
  unsigned*  HPK1 = HPK0 + 12800;

  k_init<<<dim3(1), dim3(64), 0, stream>>>(bar);
  dim3 gg(118, 12);
  k_gemm<0><<<gg, dim3(256), 0, stream>>>(words, emb, nullptr, w_ih0, b_ih0, XG);
  k_scan<<<dim3(32), dim3(384), 0, stream>>>(XG, w_hh0, b_hh0, hidden, HPK0,
                                             (unsigned*)OUT0, out + 25, bar, 1);
  k_gemm<1><<<gg, dim3(256), 0, stream>>>(words, emb, OUT0, w_ih1, b_ih1, XG);
  k_scan<<<dim3(32), dim3(384), 0, stream>>>(XG, w_hh1, b_hh1, hidden + NB * NH, HPK1,
                                             nullptr, out + 25 + NB * NH, bar + 16, 0);
  k_final<<<dim3(1), dim3(256), 0, stream>>>(out + 25 + NB * NH, fcw, fcb, out);
}

// Round 2
// 7479.272 us; speedup vs baseline: 1.2555x; 1.2555x over previous
//
#include <hip/hip_runtime.h>

#define NV 100000
#define ND 300
#define NH 512
#define NB 25
#define NT 600
#define NM 15000   // NB*NT
#define NG 1536    // 3*NH

typedef _Float16 v8h __attribute__((ext_vector_type(8)));
typedef _Float16 v4h __attribute__((ext_vector_type(4)));
typedef _Float16 v2h __attribute__((ext_vector_type(2)));
typedef float    v4f __attribute__((ext_vector_type(4)));

static __device__ __forceinline__ v8h mk8(v4h a, v4h b) {
  v8h r;
  r[0]=a[0]; r[1]=a[1]; r[2]=a[2]; r[3]=a[3];
  r[4]=b[0]; r[5]=b[1]; r[6]=b[2]; r[7]=b[3];
  return r;
}

static __device__ __forceinline__ float fsigmoid(float x) {
  // 1/(1+e^-x), single v_exp + v_rcp
  return __builtin_amdgcn_rcpf(1.f + __expf(-x));
}
static __device__ __forceinline__ float ftanh(float x) {
  // 1 - 2/(e^{2x}+1): saturation-safe (x->+inf => 1, x->-inf => -1)
  return 1.f - 2.f * __builtin_amdgcn_rcpf(1.f + __expf(2.f * x));
}

// ---------------- flag init ----------------
__global__ void k_init(unsigned* flg) {
  if (threadIdx.x < 64) flg[threadIdx.x] = 0u;
}

// ---------------- GEMM: Cxg[m][n] = sum_k A[m][k]*Bw[n][k] + bias[n], f16 out ----
// MODE 0: A = emb[words[m]] (f32, K=300). MODE 1: A = Af16 [NM][512] (f16).
template<int MODE>
__global__ __launch_bounds__(256) void k_gemm(
    const int* __restrict__ words, const float* __restrict__ emb,
    const _Float16* __restrict__ Af16,
    const float* __restrict__ Bw, const float* __restrict__ bias,
    _Float16* __restrict__ Cxg)
{
  constexpr int K   = (MODE == 0) ? ND : 512;
  constexpr int NKT = (K + 31) / 32;
  __shared__ _Float16 As[128][40];   // stride 40 f16 = 80B: 16B-aligned rows, <=2-way banks
  __shared__ _Float16 Bh[128][40];
  __shared__ _Float16 Bl[128][40];
  const int tid = threadIdx.x;
  const int m0 = blockIdx.x * 128, n0 = blockIdx.y * 128;
  const int w = tid >> 6, l = tid & 63;
  const int wm = w >> 1, wn = w & 1;
  const int l15 = l & 15, q = l >> 4;

  v4f accH[4][4], accL[4][4];
  for (int a = 0; a < 4; ++a)
    for (int b = 0; b < 4; ++b) {
      v4f z = {0.f, 0.f, 0.f, 0.f};
      accH[a][b] = z; accL[a][b] = z;
    }

#pragma unroll 1
  for (int kt = 0; kt < NKT; ++kt) {
    const int kb = kt * 32;
    // ---- stage A + B tiles (f32 -> f16 split for B) ----
    for (int jj = 0; jj < 4; ++jj) {
      const int F = tid + 256 * jj;      // 0..1023
      const int row = F >> 3;
      const int kl = (F & 7) * 4;
      // A
      if (MODE == 0) {
        const int m = m0 + row;
        float x0 = 0.f, x1 = 0.f, x2 = 0.f, x3 = 0.f;
        if (m < NM) {
          const int word = words[m];
          const float* ap = emb + (long)word * ND + kb + kl;
          if (kb + kl + 3 < K) {
            float4 v = *(const float4*)ap;
            x0 = v.x; x1 = v.y; x2 = v.z; x3 = v.w;
          } else {
            if (kb + kl + 0 < K) x0 = ap[0];
            if (kb + kl + 1 < K) x1 = ap[1];
            if (kb + kl + 2 < K) x2 = ap[2];
            if (kb + kl + 3 < K) x3 = ap[3];
          }
        }
        v4h hv; hv[0]=(_Float16)x0; hv[1]=(_Float16)x1; hv[2]=(_Float16)x2; hv[3]=(_Float16)x3;
        *(v4h*)&As[row][kl] = hv;
      } else {
        const int m = m0 + row;
        v4h hv; hv[0]=(_Float16)0; hv[1]=(_Float16)0; hv[2]=(_Float16)0; hv[3]=(_Float16)0;
        if (m < NM) hv = *(const v4h*)(Af16 + (long)m * 512 + kb + kl);
        *(v4h*)&As[row][kl] = hv;
      }
      // B (w_ih rows), split hi/lo
      {
        const int n = n0 + row;
        const float* bp = Bw + (long)n * K + kb + kl;
        float x[4] = {0.f, 0.f, 0.f, 0.f};
        if (kb + kl + 3 < K) {
          float4 v = *(const float4*)bp;
          x[0] = v.x; x[1] = v.y; x[2] = v.z; x[3] = v.w;
        } else {
          for (int c = 0; c < 4; ++c) if (kb + kl + c < K) x[c] = bp[c];
        }
        v4h bh, bl;
        for (int c = 0; c < 4; ++c) {
          _Float16 hi = (_Float16)x[c];
          bh[c] = hi;
          bl[c] = (_Float16)((x[c] - (float)hi) * 1024.f);
        }
        *(v4h*)&Bh[row][kl] = bh;
        *(v4h*)&Bl[row][kl] = bl;
      }
    }
    __syncthreads();
    // ---- MFMA ----
    v8h af[4];
    for (int mt = 0; mt < 4; ++mt) {
      const int r = wm * 64 + mt * 16 + l15;
      af[mt] = *(const v8h*)&As[r][q * 8];     // 16B-aligned (row stride 80B)
    }
    for (int nt = 0; nt < 4; ++nt) {
      const int r = wn * 64 + nt * 16 + l15;
      v8h bh = *(const v8h*)&Bh[r][q * 8];
      v8h bl = *(const v8h*)&Bl[r][q * 8];
      for (int mt = 0; mt < 4; ++mt) {
        accH[mt][nt] = __builtin_amdgcn_mfma_f32_16x16x32_f16(af[mt], bh, accH[mt][nt], 0, 0, 0);
        accL[mt][nt] = __builtin_amdgcn_mfma_f32_16x16x32_f16(af[mt], bl, accL[mt][nt], 0, 0, 0);
      }
    }
    __syncthreads();
  }
  // ---- epilogue ----
  for (int nt = 0; nt < 4; ++nt) {
    const int n = n0 + wn * 64 + nt * 16 + l15;
    const float bv = bias[n];
    for (int mt = 0; mt < 4; ++mt) {
      for (int r = 0; r < 4; ++r) {
        const int m = m0 + wm * 64 + mt * 16 + q * 4 + r;
        if (m < NM) {
          const float cv = accH[mt][nt][r] + accL[mt][nt][r] * (1.f / 1024.f) + bv;
          Cxg[(long)m * NG + n] = (_Float16)cv;
        }
      }
    }
  }
}

// ---------------- persistent GRU scan (one layer) ----------------
// grid 32 blocks x 384 thr. Block owns 16 hidden units (48 W-rows = 3 M-tiles).
// 6 waves = (mt in 0..2) x (nt in 0..1); nt=1 covers batch cols 9..24.
// Cross-block exchange: per-block monotonic step flags (no central counter).
__global__ __launch_bounds__(384) void k_scan(
    const _Float16* __restrict__ xg,   // [NM][NG] f16, includes b_ih
    const float* __restrict__ whh,     // [NG][NH] f32
    const float* __restrict__ bhh,     // [NG]
    const float* __restrict__ hinit,   // [NB][NH] f32 (layer slice of `hidden`)
    unsigned* __restrict__ hpk,        // [2][NB][256] packed f16-pair dwords
    unsigned* __restrict__ flags,      // [32] per-block step counters (monotonic)
    unsigned* __restrict__ outpk,      // [NM][256] packed (layer 0 only)
    float* __restrict__ hfin,          // d_out hidden slice [NB][NH]
    const int write_out)
{
  __shared__ _Float16 hs[NB][516];     // stride 516: 8B-aligned, ~2-way banks
  __shared__ float ghs[48][33];
  __shared__ float hprev[NB][16];      // exact fp32 recurrent state (block-local)
  const int tid = threadIdx.x;
  const int u0 = blockIdx.x * 16;
  const int w = tid >> 6, l = tid & 63;
  const int mt = w >> 1, nt = w & 1;
  const int ntb = nt ? 9 : 0;
  const int l15 = l & 15, q = l >> 4;

  // W fragments -> registers, split f16 hi/lo (lo scaled x1024)
  v8h afh[16], afl[16];
  {
    const float* wrow = whh + (long)(mt * 512 + u0 + l15) * 512 + q * 8;
    for (int ks = 0; ks < 16; ++ks) {
      float4 v0 = *(const float4*)(wrow + ks * 32);
      float4 v1 = *(const float4*)(wrow + ks * 32 + 4);
      float xs[8] = {v0.x, v0.y, v0.z, v0.w, v1.x, v1.y, v1.z, v1.w};
      v8h hh, hl;
      for (int j = 0; j < 8; ++j) {
        _Float16 hi = (_Float16)xs[j];
        hh[j] = hi;
        hl[j] = (_Float16)((xs[j] - (float)hi) * 1024.f);
      }
      afh[ks] = hh; afl[ks] = hl;
    }
  }
  // initial h stage
  for (int idx = tid; idx < NB * NH; idx += 384) {
    const int b = idx >> 9, k = idx & 511;
    hs[b][k] = (_Float16)hinit[idx];
  }
  for (int t2 = tid; t2 < 400; t2 += 384) {
    const int b = t2 >> 4, i = t2 & 15;
    hprev[b][i] = hinit[b * 512 + u0 + i];
  }
  __syncthreads();

  const bool ga = (tid < 200);         // gate tasks: (b 0..24) x (j 0..7), 2 units each
  const int gb = tid >> 3, gj = tid & 7;

  // loop-invariant gate constants + xg(0) prefetch
  float bh_r0 = 0.f, bh_z0 = 0.f, bh_n0 = 0.f, bh_r1 = 0.f, bh_z1 = 0.f, bh_n1 = 0.f;
  const _Float16* xp = xg + (long)(ga ? gb * NT : 0) * NG + u0 + 2 * gj;
  v2h xr = {(_Float16)0, (_Float16)0}, xz = xr, xn2 = xr;
  if (ga) {
    const int i0 = 2 * gj, ug0 = u0 + i0;
    bh_r0 = bhh[ug0];     bh_r1 = bhh[ug0 + 1];
    bh_z0 = bhh[512 + ug0];  bh_z1 = bhh[512 + ug0 + 1];
    bh_n0 = bhh[1024 + ug0]; bh_n1 = bhh[1024 + ug0 + 1];
    xr  = *(const v2h*)xp;
    xz  = *(const v2h*)(xp + 512);
    xn2 = *(const v2h*)(xp + 1024);
  }

#pragma unroll 1
  for (int t = 0; t < NT; ++t) {
    // prefetch xg(t+1): latency hidden behind this step's MFMA phase
    v2h pr = {(_Float16)0, (_Float16)0}, pz = pr, pn = pr;
    if (ga && t + 1 < NT) {
      const _Float16* q2 = xp + NG;
      pr = *(const v2h*)q2;
      pz = *(const v2h*)(q2 + 512);
      pn = *(const v2h*)(q2 + 1024);
    }
    // gh = W_chunk * h^T via MFMA (4 independent acc chains)
    const int bcol = ntb + l15;
    v4f aH0 = {0.f,0.f,0.f,0.f}, aH1 = {0.f,0.f,0.f,0.f};
    v4f aL0 = {0.f,0.f,0.f,0.f}, aL1 = {0.f,0.f,0.f,0.f};
    for (int ks = 0; ks < 16; ks += 2) {
      const int k = ks * 32 + q * 8;
      v8h b0 = mk8(*(const v4h*)&hs[bcol][k],      *(const v4h*)&hs[bcol][k + 4]);
      v8h b1 = mk8(*(const v4h*)&hs[bcol][k + 32], *(const v4h*)&hs[bcol][k + 36]);
      aH0 = __builtin_amdgcn_mfma_f32_16x16x32_f16(afh[ks],     b0, aH0, 0, 0, 0);
      aL0 = __builtin_amdgcn_mfma_f32_16x16x32_f16(afl[ks],     b0, aL0, 0, 0, 0);
      aH1 = __builtin_amdgcn_mfma_f32_16x16x32_f16(afh[ks + 1], b1, aH1, 0, 0, 0);
      aL1 = __builtin_amdgcn_mfma_f32_16x16x32_f16(afl[ks + 1], b1, aL1, 0, 0, 0);
    }
    {
      const int row = mt * 16 + q * 4;
      for (int r = 0; r < 4; ++r)
        ghs[row + r][bcol] = (aH0[r] + aH1[r]) + (aL0[r] + aL1[r]) * (1.f / 1024.f);
    }
    __syncthreads();
    // gate math (fp32), write packed-f16 h via device-scope stores
    if (ga) {
      const int i0 = 2 * gj, i1 = i0 + 1;
      float hr0 = ghs[i0][gb]      + bh_r0;
      float hz0 = ghs[16 + i0][gb] + bh_z0;
      float hn0 = ghs[32 + i0][gb] + bh_n0;
      float hr1 = ghs[i1][gb]      + bh_r1;
      float hz1 = ghs[16 + i1][gb] + bh_z1;
      float hn1 = ghs[32 + i1][gb] + bh_n1;
      float r0 = fsigmoid((float)xr[0] + hr0);
      float z0 = fsigmoid((float)xz[0] + hz0);
      float n0 = ftanh((float)xn2[0] + r0 * hn0);
      float r1 = fsigmoid((float)xr[1] + hr1);
      float z1 = fsigmoid((float)xz[1] + hz1);
      float n1 = ftanh((float)xn2[1] + r1 * hn1);
      float hp0 = hprev[gb][i0], hp1 = hprev[gb][i1];
      float h0 = (1.f - z0) * n0 + z0 * hp0;
      float h1 = (1.f - z1) * n1 + z1 * hp1;
      hprev[gb][i0] = h0; hprev[gb][i1] = h1;
      _Float16 f0 = (_Float16)h0, f1 = (_Float16)h1;
      unsigned pk = (unsigned)(*(unsigned short*)&f0) | ((unsigned)(*(unsigned short*)&f1) << 16);
      const int di = gb * 256 + (u0 >> 1) + gj;
      __hip_atomic_store(&hpk[(t & 1) * 6400 + di], pk, __ATOMIC_RELAXED, __HIP_MEMORY_SCOPE_AGENT);
      if (write_out) outpk[(long)(gb * NT + t) * 256 + (u0 >> 1) + gj] = pk;
      if (t == NT - 1) { hfin[gb * 512 + u0 + i0] = h0; hfin[gb * 512 + u0 + i1] = h1; }
    }
    __syncthreads();   // drains each wave's vmcnt -> all block stores at coherence point
    if (t < NT - 1) {
      // signal: per-block monotonic flag
      if (tid == 0)
        __hip_atomic_store(&flags[blockIdx.x], (unsigned)(t + 1),
                           __ATOMIC_RELEASE, __HIP_MEMORY_SCOPE_AGENT);
      // every wave polls all 32 flags (lane l -> flag[l]); exec-mask loop = all done
      if (l < 32) {
        const unsigned tgt = (unsigned)(t + 1);
        while (__hip_atomic_load(&flags[l], __ATOMIC_RELAXED, __HIP_MEMORY_SCOPE_AGENT) < tgt) {}
      }
      // restage h(t+1): 8B coherence-point loads, each wave writes its own share
      const unsigned long long* src = (const unsigned long long*)(hpk + (t & 1) * 6400);
      for (int idx = tid; idx < 3200; idx += 384) {
        unsigned long long v = __hip_atomic_load(&src[idx], __ATOMIC_RELAXED,
                                                 __HIP_MEMORY_SCOPE_AGENT);
        const int b = idx >> 7, k4 = (idx & 127) * 4;
        *(unsigned long long*)&hs[b][k4] = v;
      }
      __syncthreads();
    }
    xr = pr; xz = pz; xn2 = pn; xp += NG;
  }
}

// ---------------- final FC + sigmoid ----------------
__global__ __launch_bounds__(256) void k_final(
    const float* __restrict__ h1, const float* __restrict__ fcw,
    const float* __restrict__ fcb, float* __restrict__ sig)
{
  __shared__ float red[25][8];
  const int tid = threadIdx.x;
  const int b = tid >> 3, p = tid & 7;
  if (b < 25) {
    float s = 0.f;
    for (int k = p * 64; k < p * 64 + 64; ++k) s += h1[b * 512 + k] * fcw[k];
    red[b][p] = s;
  }
  __syncthreads();
  if (b < 25 && p == 0) {
    float d = red[b][0] + red[b][1] + red[b][2] + red[b][3]
            + red[b][4] + red[b][5] + red[b][6] + red[b][7];
    sig[b] = 1.f / (1.f + __expf(-(d + fcb[0])));
  }
}

extern "C" void kernel_launch(void* const* d_in, const int* in_sizes, int n_in,
                              void* d_out, int out_size, void* d_ws, size_t ws_size,
                              hipStream_t stream)
{
  (void)in_sizes; (void)n_in; (void)out_size;
  const int*   words  = (const int*)d_in[0];
  const float* hidden = (const float*)d_in[1];
  const float* emb    = (const float*)d_in[2];
  const float* w_ih0  = (const float*)d_in[3];
  const float* w_hh0  = (const float*)d_in[4];
  const float* b_ih0  = (const float*)d_in[5];
  const float* b_hh0  = (const float*)d_in[6];
  const float* w_ih1  = (const float*)d_in[7];
  const float* w_hh1  = (const float*)d_in[8];
  const float* b_ih1  = (const float*)d_in[9];
  const float* b_hh1  = (const float*)d_in[10];
  const float* fcw    = (const float*)d_in[11];
  const float* fcb    = (const float*)d_in[12];
  float* out = (float*)d_out;
  char* ws = (char*)d_ws;

  // ws layout: [0,256) flags (2 x 32 dwords) | XG f16 46.08MB | OUT0 f16 15.36MB | HPK 2x2x25.6KB
  const size_t NEED = 256 + 46080000 + 15360000 + 102400;
  if (ws_size < NEED) return;  // scratch too small: fail loudly via absmax, not corruption

  unsigned*  flg0 = (unsigned*)ws;
  unsigned*  flg1 = flg0 + 32;
  _Float16*  XG   = (_Float16*)(ws + 256);
  _Float16*  OUT0 = (_Float16*)(ws + 256 + 46080000);
  unsigned*  HPK0 = (unsigned*)(ws + 256 + 46080000 + 15360000);
  unsigned*  HPK1 = HPK0 + 12800;

  k_init<<<dim3(1), dim3(64), 0, stream>>>(flg0);
  dim3 gg(118, 12);
  k_gemm<0><<<gg, dim3(256), 0, stream>>>(words, emb, nullptr, w_ih0, b_ih0, XG);
  k_scan<<<dim3(32), dim3(384), 0, stream>>>(XG, w_hh0, b_hh0, hidden, HPK0, flg0,
                                             (unsigned*)OUT0, out + 25, 1);
  k_gemm<1><<<gg, dim3(256), 0, stream>>>(words, emb, OUT0, w_ih1, b_ih1, XG);
  k_scan<<<dim3(32), dim3(384), 0, stream>>>(XG, w_hh1, b_hh1, hidden + NB * NH, HPK1, flg1,
                                             nullptr, out + 25 + NB * NH, 0);
  k_final<<<dim3(1), dim3(256), 0, stream>>>(out + 25 + NB * NH, fcw, fcb, out);
}

// Round 3
// 5115.712 us; speedup vs baseline: 1.8356x; 1.4620x over previous
//
#include <hip/hip_runtime.h>

#define NV 100000
#define ND 300
#define NH 512
#define NB 25
#define NT 600
#define NM 15000   // NB*NT
#define NG 1536    // 3*NH

typedef _Float16 v8h __attribute__((ext_vector_type(8)));
typedef _Float16 v4h __attribute__((ext_vector_type(4)));
typedef _Float16 v2h __attribute__((ext_vector_type(2)));
typedef float    v4f __attribute__((ext_vector_type(4)));
typedef unsigned long long ull;

static __device__ __forceinline__ float fsigmoid(float x) {
  return __builtin_amdgcn_rcpf(1.f + __expf(-x));
}
static __device__ __forceinline__ float ftanh(float x) {
  // 1 - 2/(e^{2x}+1): saturation-safe
  return 1.f - 2.f * __builtin_amdgcn_rcpf(1.f + __expf(2.f * x));
}

// ---------------- GEMM: Cxg[m][n] = sum_k A[m][k]*Bw[n][k] + bias[n], f16 out ----
// MODE 0: A = emb[words[m]] (f32, K=300). MODE 1: A = Af16 [NM][512] (f16).
template<int MODE>
__global__ __launch_bounds__(256) void k_gemm(
    const int* __restrict__ words, const float* __restrict__ emb,
    const _Float16* __restrict__ Af16,
    const float* __restrict__ Bw, const float* __restrict__ bias,
    _Float16* __restrict__ Cxg)
{
  constexpr int K   = (MODE == 0) ? ND : 512;
  constexpr int NKT = (K + 31) / 32;
  __shared__ _Float16 As[128][40];   // stride 40 f16 = 80B: 16B-aligned rows, <=2-way banks
  __shared__ _Float16 Bh[128][40];
  __shared__ _Float16 Bl[128][40];
  const int tid = threadIdx.x;
  const int m0 = blockIdx.x * 128, n0 = blockIdx.y * 128;
  const int w = tid >> 6, l = tid & 63;
  const int wm = w >> 1, wn = w & 1;
  const int l15 = l & 15, q = l >> 4;

  v4f accH[4][4], accL[4][4];
  for (int a = 0; a < 4; ++a)
    for (int b = 0; b < 4; ++b) {
      v4f z = {0.f, 0.f, 0.f, 0.f};
      accH[a][b] = z; accL[a][b] = z;
    }

#pragma unroll 1
  for (int kt = 0; kt < NKT; ++kt) {
    const int kb = kt * 32;
    for (int jj = 0; jj < 4; ++jj) {
      const int F = tid + 256 * jj;      // 0..1023
      const int row = F >> 3;
      const int kl = (F & 7) * 4;
      // A
      if (MODE == 0) {
        const int m = m0 + row;
        float x0 = 0.f, x1 = 0.f, x2 = 0.f, x3 = 0.f;
        if (m < NM) {
          const int word = words[m];
          const float* ap = emb + (long)word * ND + kb + kl;
          if (kb + kl + 3 < K) {
            float4 v = *(const float4*)ap;
            x0 = v.x; x1 = v.y; x2 = v.z; x3 = v.w;
          } else {
            if (kb + kl + 0 < K) x0 = ap[0];
            if (kb + kl + 1 < K) x1 = ap[1];
            if (kb + kl + 2 < K) x2 = ap[2];
            if (kb + kl + 3 < K) x3 = ap[3];
          }
        }
        v4h hv; hv[0]=(_Float16)x0; hv[1]=(_Float16)x1; hv[2]=(_Float16)x2; hv[3]=(_Float16)x3;
        *(v4h*)&As[row][kl] = hv;
      } else {
        const int m = m0 + row;
        v4h hv; hv[0]=(_Float16)0; hv[1]=(_Float16)0; hv[2]=(_Float16)0; hv[3]=(_Float16)0;
        if (m < NM) hv = *(const v4h*)(Af16 + (long)m * 512 + kb + kl);
        *(v4h*)&As[row][kl] = hv;
      }
      // B (w_ih rows), split hi/lo
      {
        const int n = n0 + row;
        const float* bp = Bw + (long)n * K + kb + kl;
        float x[4] = {0.f, 0.f, 0.f, 0.f};
        if (kb + kl + 3 < K) {
          float4 v = *(const float4*)bp;
          x[0] = v.x; x[1] = v.y; x[2] = v.z; x[3] = v.w;
        } else {
          for (int c = 0; c < 4; ++c) if (kb + kl + c < K) x[c] = bp[c];
        }
        v4h bh, bl;
        for (int c = 0; c < 4; ++c) {
          _Float16 hi = (_Float16)x[c];
          bh[c] = hi;
          bl[c] = (_Float16)((x[c] - (float)hi) * 1024.f);
        }
        *(v4h*)&Bh[row][kl] = bh;
        *(v4h*)&Bl[row][kl] = bl;
      }
    }
    __syncthreads();
    v8h af[4];
    for (int mt = 0; mt < 4; ++mt) {
      const int r = wm * 64 + mt * 16 + l15;
      af[mt] = *(const v8h*)&As[r][q * 8];
    }
    for (int nt = 0; nt < 4; ++nt) {
      const int r = wn * 64 + nt * 16 + l15;
      v8h bh = *(const v8h*)&Bh[r][q * 8];
      v8h bl = *(const v8h*)&Bl[r][q * 8];
      for (int mt = 0; mt < 4; ++mt) {
        accH[mt][nt] = __builtin_amdgcn_mfma_f32_16x16x32_f16(af[mt], bh, accH[mt][nt], 0, 0, 0);
        accL[mt][nt] = __builtin_amdgcn_mfma_f32_16x16x32_f16(af[mt], bl, accL[mt][nt], 0, 0, 0);
      }
    }
    __syncthreads();
  }
  for (int nt = 0; nt < 4; ++nt) {
    const int n = n0 + wn * 64 + nt * 16 + l15;
    const float bv = bias[n];
    for (int mt = 0; mt < 4; ++mt) {
      for (int r = 0; r < 4; ++r) {
        const int m = m0 + wm * 64 + mt * 16 + q * 4 + r;
        if (m < NM) {
          const float cv = accH[mt][nt][r] + accL[mt][nt][r] * (1.f / 1024.f) + bv;
          Cxg[(long)m * NG + n] = (_Float16)cv;
        }
      }
    }
  }
}

// ---- tagged-poll restage: issue all loads, then check (one RT per sweep) ----
template<int K0, int NK>
static __device__ __forceinline__ void restage_chunk(
    const ull* __restrict__ src, unsigned want, int tid, _Float16 (*hs)[520])
{
  unsigned ok = 0;
  const unsigned full = (1u << NK) - 1;
#pragma unroll
  for (int k = 0; k < NK; ++k)
    if (tid + 384 * (K0 + k) >= 6400) ok |= 1u << k;
  while (ok != full) {
    ull vals[NK];
#pragma unroll
    for (int k = 0; k < NK; ++k)
      if (!(ok & (1u << k)))
        vals[k] = __hip_atomic_load(&src[tid + 384 * (K0 + k)],
                                    __ATOMIC_RELAXED, __HIP_MEMORY_SCOPE_AGENT);
#pragma unroll
    for (int k = 0; k < NK; ++k)
      if (!(ok & (1u << k)) && (unsigned)(vals[k] >> 32) == want) {
        ok |= 1u << k;
        const int idx = tid + 384 * (K0 + k);
        *(unsigned*)&hs[idx >> 8][(idx & 255) * 2] = (unsigned)vals[k];
      }
  }
}

// ---------------- persistent GRU scan (one layer) ----------------
// 32 blocks x 384 thr. Block owns 16 hidden units (48 W-rows in registers).
// Exchange: single 64-bit tagged atomic per h-pair, (step<<32)|f16x2.
// No flags, no store-ack drain: readers poll the data itself (2 parity bufs).
__global__ __launch_bounds__(384) void k_scan(
    const _Float16* __restrict__ xg,   // [NM][NG] f16, includes b_ih
    const float* __restrict__ whh,     // [NG][NH] f32
    const float* __restrict__ bhh,     // [NG]
    const float* __restrict__ hinit,   // [NB][NH] f32
    ull* __restrict__ hpk,             // [2][6400] tagged h-pairs
    unsigned* __restrict__ outpk,      // [NM][256] packed (layer 0 only)
    float* __restrict__ hfin,          // d_out hidden slice [NB][NH]
    const int write_out)
{
  __shared__ __align__(16) _Float16 hs[NB][520];  // stride 520: 16B-aligned b128 rows
  __shared__ float ghs[48][33];
  __shared__ float hprev[NB][16];      // exact fp32 recurrent state (block-local)
  const int tid = threadIdx.x;
  const int u0 = blockIdx.x * 16;
  const int w = tid >> 6, l = tid & 63;
  const int mt = w >> 1, nt = w & 1;
  const int ntb = nt ? 9 : 0;
  const int l15 = l & 15, q = l >> 4;

  // W fragments -> registers, split f16 hi/lo (lo scaled x1024)
  v8h afh[16], afl[16];
  {
    const float* wrow = whh + (long)(mt * 512 + u0 + l15) * 512 + q * 8;
    for (int ks = 0; ks < 16; ++ks) {
      float4 v0 = *(const float4*)(wrow + ks * 32);
      float4 v1 = *(const float4*)(wrow + ks * 32 + 4);
      float xs[8] = {v0.x, v0.y, v0.z, v0.w, v1.x, v1.y, v1.z, v1.w};
      v8h hh, hl;
      for (int j = 0; j < 8; ++j) {
        _Float16 hi = (_Float16)xs[j];
        hh[j] = hi;
        hl[j] = (_Float16)((xs[j] - (float)hi) * 1024.f);
      }
      afh[ks] = hh; afl[ks] = hl;
    }
  }
  for (int idx = tid; idx < NB * NH; idx += 384) {
    const int b = idx >> 9, k = idx & 511;
    hs[b][k] = (_Float16)hinit[idx];
  }
  for (int t2 = tid; t2 < 400; t2 += 384) {
    const int b = t2 >> 4, i = t2 & 15;
    hprev[b][i] = hinit[b * 512 + u0 + i];
  }
  __syncthreads();

  const bool ga = (tid < 200);         // (b 0..24) x (j 0..7), 2 units each
  const int gb = tid >> 3, gj = tid & 7;

  float bh_r0 = 0.f, bh_z0 = 0.f, bh_n0 = 0.f, bh_r1 = 0.f, bh_z1 = 0.f, bh_n1 = 0.f;
  const _Float16* xp = xg + (long)(ga ? gb * NT : 0) * NG + u0 + 2 * gj;
  v2h xr = {(_Float16)0, (_Float16)0}, xz = xr, xn2 = xr;
  if (ga) {
    const int i0 = 2 * gj, ug0 = u0 + i0;
    bh_r0 = bhh[ug0];        bh_r1 = bhh[ug0 + 1];
    bh_z0 = bhh[512 + ug0];  bh_z1 = bhh[512 + ug0 + 1];
    bh_n0 = bhh[1024 + ug0]; bh_n1 = bhh[1024 + ug0 + 1];
    xr  = *(const v2h*)xp;
    xz  = *(const v2h*)(xp + 512);
    xn2 = *(const v2h*)(xp + 1024);
  }

#pragma unroll 1
  for (int t = 0; t < NT; ++t) {
    // prefetch xg(t+1) behind MFMA
    v2h pr = {(_Float16)0, (_Float16)0}, pz = pr, pn = pr;
    if (ga && t + 1 < NT) {
      const _Float16* q2 = xp + NG;
      pr = *(const v2h*)q2;
      pz = *(const v2h*)(q2 + 512);
      pn = *(const v2h*)(q2 + 1024);
    }
    // gh = W_chunk * h^T via MFMA (4 independent acc chains)
    const int bcol = ntb + l15;
    v4f aH0 = {0.f,0.f,0.f,0.f}, aH1 = {0.f,0.f,0.f,0.f};
    v4f aL0 = {0.f,0.f,0.f,0.f}, aL1 = {0.f,0.f,0.f,0.f};
    for (int ks = 0; ks < 16; ks += 2) {
      const int k = ks * 32 + q * 8;
      v8h b0 = *(const v8h*)&hs[bcol][k];        // b128, 16B-aligned
      v8h b1 = *(const v8h*)&hs[bcol][k + 32];
      aH0 = __builtin_amdgcn_mfma_f32_16x16x32_f16(afh[ks],     b0, aH0, 0, 0, 0);
      aL0 = __builtin_amdgcn_mfma_f32_16x16x32_f16(afl[ks],     b0, aL0, 0, 0, 0);
      aH1 = __builtin_amdgcn_mfma_f32_16x16x32_f16(afh[ks + 1], b1, aH1, 0, 0, 0);
      aL1 = __builtin_amdgcn_mfma_f32_16x16x32_f16(afl[ks + 1], b1, aL1, 0, 0, 0);
    }
    {
      const int row = mt * 16 + q * 4;
      for (int r = 0; r < 4; ++r)
        ghs[row + r][bcol] = (aH0[r] + aH1[r]) + (aL0[r] + aL1[r]) * (1.f / 1024.f);
    }
    __syncthreads();   // ghs ready; also: all waves done reading hs -> restage may write it
    // gate math (fp32), fire-and-forget tagged 64b store
    if (ga) {
      const int i0 = 2 * gj, i1 = i0 + 1;
      float hr0 = ghs[i0][gb]      + bh_r0;
      float hz0 = ghs[16 + i0][gb] + bh_z0;
      float hn0 = ghs[32 + i0][gb] + bh_n0;
      float hr1 = ghs[i1][gb]      + bh_r1;
      float hz1 = ghs[16 + i1][gb] + bh_z1;
      float hn1 = ghs[32 + i1][gb] + bh_n1;
      float r0 = fsigmoid((float)xr[0] + hr0);
      float z0 = fsigmoid((float)xz[0] + hz0);
      float n0 = ftanh((float)xn2[0] + r0 * hn0);
      float r1 = fsigmoid((float)xr[1] + hr1);
      float z1 = fsigmoid((float)xz[1] + hz1);
      float n1 = ftanh((float)xn2[1] + r1 * hn1);
      float hp0 = hprev[gb][i0], hp1 = hprev[gb][i1];
      float h0 = (1.f - z0) * n0 + z0 * hp0;
      float h1 = (1.f - z1) * n1 + z1 * hp1;
      hprev[gb][i0] = h0; hprev[gb][i1] = h1;
      _Float16 f0 = (_Float16)h0, f1 = (_Float16)h1;
      unsigned pk = (unsigned)(*(unsigned short*)&f0) | ((unsigned)(*(unsigned short*)&f1) << 16);
      const int di = gb * 256 + (u0 >> 1) + gj;
      if (t < NT - 1)
        __hip_atomic_store(&hpk[(size_t)((t + 1) & 1) * 6400 + di],
                           ((ull)(unsigned)(t + 1) << 32) | (ull)pk,
                           __ATOMIC_RELAXED, __HIP_MEMORY_SCOPE_AGENT);
      if (write_out) outpk[(long)(gb * NT + t) * 256 + (u0 >> 1) + gj] = pk;
      if (t == NT - 1) { hfin[gb * 512 + u0 + i0] = h0; hfin[gb * 512 + u0 + i1] = h1; }
    }
    // restage h(t+1): poll tagged data directly (no flags, no ack chain)
    if (t < NT - 1) {
      const ull* src = hpk + (size_t)((t + 1) & 1) * 6400;
      const unsigned want = (unsigned)(t + 1);
      restage_chunk<0, 9>(src, want, tid, hs);
      restage_chunk<9, 8>(src, want, tid, hs);
      __syncthreads();
    }
    xr = pr; xz = pz; xn2 = pn; xp += NG;
  }
}

// ---------------- final FC + sigmoid ----------------
__global__ __launch_bounds__(256) void k_final(
    const float* __restrict__ h1, const float* __restrict__ fcw,
    const float* __restrict__ fcb, float* __restrict__ sig)
{
  __shared__ float red[25][8];
  const int tid = threadIdx.x;
  const int b = tid >> 3, p = tid & 7;
  if (b < 25) {
    float s = 0.f;
    for (int k = p * 64; k < p * 64 + 64; ++k) s += h1[b * 512 + k] * fcw[k];
    red[b][p] = s;
  }
  __syncthreads();
  if (b < 25 && p == 0) {
    float d = red[b][0] + red[b][1] + red[b][2] + red[b][3]
            + red[b][4] + red[b][5] + red[b][6] + red[b][7];
    sig[b] = 1.f / (1.f + __expf(-(d + fcb[0])));
  }
}

extern "C" void kernel_launch(void* const* d_in, const int* in_sizes, int n_in,
                              void* d_out, int out_size, void* d_ws, size_t ws_size,
                              hipStream_t stream)
{
  (void)in_sizes; (void)n_in; (void)out_size;
  const int*   words  = (const int*)d_in[0];
  const float* hidden = (const float*)d_in[1];
  const float* emb    = (const float*)d_in[2];
  const float* w_ih0  = (const float*)d_in[3];
  const float* w_hh0  = (const float*)d_in[4];
  const float* b_ih0  = (const float*)d_in[5];
  const float* b_hh0  = (const float*)d_in[6];
  const float* w_ih1  = (const float*)d_in[7];
  const float* w_hh1  = (const float*)d_in[8];
  const float* b_ih1  = (const float*)d_in[9];
  const float* b_hh1  = (const float*)d_in[10];
  const float* fcw    = (const float*)d_in[11];
  const float* fcb    = (const float*)d_in[12];
  float* out = (float*)d_out;
  char* ws = (char*)d_ws;

  // ws: [0,256) pad | XG f16 46.08MB | OUT0 f16 15.36MB | HPK 2 layers x 2 bufs x 6400 ull
  const size_t NEED = 256 + 46080000 + 15360000 + 204800;
  if (ws_size < NEED) return;

  _Float16* XG   = (_Float16*)(ws + 256);
  _Float16* OUT0 = (_Float16*)(ws + 256 + 46080000);
  ull*      HPK0 = (ull*)(ws + 256 + 46080000 + 15360000);
  ull*      HPK1 = HPK0 + 12800;

  dim3 gg(118, 12);
  k_gemm<0><<<gg, dim3(256), 0, stream>>>(words, emb, nullptr, w_ih0, b_ih0, XG);
  k_scan<<<dim3(32), dim3(384), 0, stream>>>(XG, w_hh0, b_hh0, hidden, HPK0,
                                             (unsigned*)OUT0, out + 25, 1);
  k_gemm<1><<<gg, dim3(256), 0, stream>>>(words, emb, OUT0, w_ih1, b_ih1, XG);
  k_scan<<<dim3(32), dim3(384), 0, stream>>>(XG, w_hh1, b_hh1, hidden + NB * NH, HPK1,
                                             nullptr, out + 25 + NB * NH, 0);
  k_final<<<dim3(1), dim3(256), 0, stream>>>(out + 25 + NB * NH, fcw, fcb, out);
}